// Round 2
// baseline (79.956 us; speedup 1.0000x reference)
//
#include <hip/hip_runtime.h>

// Problem constants (from setup_inputs): B=8, C=3, H=W=256, mask (B,1,H,W)
#define BB 8
#define CC 3
#define HH 256
#define WW 256
#define HWC (HH * WW)

// BIG = H+W = 512 ; BIG^2 = 262144. Any achievable D^2 <= 255^2*2 = 130050 < BIG^2,
// so (d2 >= BIG^2) <=> image has no border pixels (reference leaves D = 0 then).
#define BIGF 512.0f
#define BIG2F 262144.0f

// log2(0.99)
#define LOG2G (-0.014499569695115089f)
// 1 / (B*C*H*W)
#define INV_N (1.0f / 1572864.0f)

// ---------------------------------------------------------------------------
// Kernel A: border = (maxpool3x3(mask) - mask) > 0.5 ; also zero d_out.
// One thread per (b,r,c).
__global__ __launch_bounds__(256) void border_kernel(
    const float* __restrict__ mask, float* __restrict__ border,
    float* __restrict__ out) {
  int idx = blockIdx.x * blockDim.x + threadIdx.x;
  if (idx == 0) out[0] = 0.0f;
  if (idx >= BB * HWC) return;
  int c = idx % WW;
  int r = (idx / WW) % HH;
  int b = idx / HWC;
  const float* mb = mask + b * HWC;
  float m = mb[r * WW + c];
  float mx = m;
  int r0 = (r > 0) ? r - 1 : 0, r1 = (r < HH - 1) ? r + 1 : HH - 1;
  int c0 = (c > 0) ? c - 1 : 0, c1 = (c < WW - 1) ? c + 1 : WW - 1;
  for (int rr = r0; rr <= r1; ++rr)
    for (int cc = c0; cc <= c1; ++cc)
      mx = fmaxf(mx, mb[rr * WW + cc]);
  border[idx] = ((mx - m) > 0.5f) ? 1.0f : 0.0f;
}

// ---------------------------------------------------------------------------
// Kernel B: per-column vertical distance to nearest border pixel, two scans,
// capped at BIG; writes g^2. One thread per (b,w) column; in-place over the
// down-scan buffer.
__global__ __launch_bounds__(256) void vdist_kernel(
    const float* __restrict__ border, float* __restrict__ g2) {
  int t = blockIdx.x * blockDim.x + threadIdx.x;  // b*W + w
  if (t >= BB * WW) return;
  int w = t % WW;
  int b = t / WW;
  const float* bp = border + b * HWC + w;
  float* gp = g2 + b * HWC + w;
  float carry = BIGF;
  for (int r = 0; r < HH; ++r) {
    carry = (bp[r * WW] > 0.5f) ? 0.0f : carry + 1.0f;
    gp[r * WW] = carry;  // down-scan value
  }
  carry = BIGF;
  for (int r = HH - 1; r >= 0; --r) {
    carry = (bp[r * WW] > 0.5f) ? 0.0f : carry + 1.0f;
    float g = fminf(fminf(gp[r * WW], carry), BIGF);
    gp[r * WW] = g * g;
  }
}

// ---------------------------------------------------------------------------
// Kernel C: per-row min-plus over columns (exact EDT stage 2), then fused
// weight + L1 + mean reduction. One block (256 threads) per (b,r) row.
__global__ __launch_bounds__(256) void row_loss_kernel(
    const float* __restrict__ g2, const float* __restrict__ mask,
    const float* __restrict__ rec, const float* __restrict__ im,
    float* __restrict__ out) {
  __shared__ float srow[WW];
  __shared__ float swave[4];
  int br = blockIdx.x;  // b*H + r
  int b = br / HH;
  int r = br % HH;
  int c = threadIdx.x;
  int base = b * HWC + r * WW;

  srow[c] = g2[base + c];
  __syncthreads();

  float cf = (float)c;
  float d2 = 4.0f * BIG2F;
#pragma unroll 8
  for (int cp = 0; cp < WW; ++cp) {
    float diff = cf - (float)cp;
    d2 = fminf(d2, diff * diff + srow[cp]);
  }

  float m = mask[base + c];
  float dist = (d2 >= BIG2F) ? 0.0f : sqrtf(d2);
  float dm = dist * m;                  // reference: dist = D * mask
  float wgt = exp2f(dm * LOG2G) * m;    // gamma^dist * mask

  int pbase = b * CC * HWC + r * WW + c;
  float acc = 0.0f;
#pragma unroll
  for (int ch = 0; ch < CC; ++ch) {
    float d = rec[pbase + ch * HWC] - im[pbase + ch * HWC];
    acc += fabsf(d);
  }
  float local = wgt * acc;

  // wave (64-lane) reduction
#pragma unroll
  for (int off = 32; off > 0; off >>= 1) local += __shfl_down(local, off, 64);
  int lane = c & 63, wid = c >> 6;
  if (lane == 0) swave[wid] = local;
  __syncthreads();
  if (c == 0) {
    float s = swave[0] + swave[1] + swave[2] + swave[3];
    atomicAdd(out, s * INV_N);
  }
}

// ---------------------------------------------------------------------------
extern "C" void kernel_launch(void* const* d_in, const int* in_sizes, int n_in,
                              void* d_out, int out_size, void* d_ws,
                              size_t ws_size, hipStream_t stream) {
  const float* rec = (const float*)d_in[0];
  const float* im = (const float*)d_in[1];
  const float* mask = (const float*)d_in[2];
  float* out = (float*)d_out;

  float* border = (float*)d_ws;                  // B*H*W floats = 2 MB
  float* g2 = (float*)d_ws + (size_t)BB * HWC;   // B*H*W floats = 2 MB

  int npix = BB * HWC;
  border_kernel<<<(npix + 255) / 256, 256, 0, stream>>>(mask, border, out);
  vdist_kernel<<<(BB * WW + 255) / 256, 256, 0, stream>>>(border, g2);
  row_loss_kernel<<<BB * HH, 256, 0, stream>>>(g2, mask, rec, im, out);
}

// Round 3
// 44.064 us; speedup vs baseline: 1.8145x; 1.8145x over previous
//
#include <hip/hip_runtime.h>

// Problem constants: B=8, C=3, H=W=256, mask (B,1,H,W)
#define BB 8
#define CC 3
#define HH 256
#define WW 256
#define HWC (HH * WW)

// BIG = H+W = 512 ; BIG^2 = 262144. Any achievable D^2 <= 2*255^2 < BIG^2,
// so (d2 >= BIG^2) <=> image has no border pixels (reference leaves D = 0).
#define BIGF 512.0f
#define BIG2F 262144.0f

#define LOG2G (-0.014499569695115089f)  // log2(0.99)
#define INV_N (1.0f / 1572864.0f)       // 1/(B*C*H*W)

// ---------------------------------------------------------------------------
// Kernel A: border = (maxpool3x3(mask) - mask) > 0.5 ; also zero d_out.
// One thread per 8 horizontal pixels; fixed 3-row clamped window (duplicate
// rows at the image edge are harmless under max).
__global__ __launch_bounds__(256) void border_kernel(
    const float* __restrict__ mask, float* __restrict__ border,
    float* __restrict__ out) {
  int idx = blockIdx.x * blockDim.x + threadIdx.x;  // BB*HH*(WW/8) threads
  if (idx == 0) out[0] = 0.0f;
  const int WT = WW / 8;  // 32
  int c8 = (idx % WT) * 8;
  int r = (idx / WT) % HH;
  int b = idx / (WT * HH);
  const float* mb = mask + b * HWC;

  float cmax[10];  // columns c8-1 .. c8+8
#pragma unroll
  for (int j = 0; j < 10; ++j) cmax[j] = 0.0f;
  float m[8];

  int rrs[3] = {r > 0 ? r - 1 : 0, r, r < HH - 1 ? r + 1 : HH - 1};
#pragma unroll
  for (int k = 0; k < 3; ++k) {
    const float* row = mb + rrs[k] * WW;
    float4 M0 = *(const float4*)(row + c8);
    float4 M1 = *(const float4*)(row + c8 + 4);
    float lw = (c8 > 0) ? row[c8 - 1] : 0.0f;
    float rx = (c8 + 8 < WW) ? row[c8 + 8] : 0.0f;
    cmax[0] = fmaxf(cmax[0], lw);
    cmax[1] = fmaxf(cmax[1], M0.x);
    cmax[2] = fmaxf(cmax[2], M0.y);
    cmax[3] = fmaxf(cmax[3], M0.z);
    cmax[4] = fmaxf(cmax[4], M0.w);
    cmax[5] = fmaxf(cmax[5], M1.x);
    cmax[6] = fmaxf(cmax[6], M1.y);
    cmax[7] = fmaxf(cmax[7], M1.z);
    cmax[8] = fmaxf(cmax[8], M1.w);
    cmax[9] = fmaxf(cmax[9], rx);
    if (k == 1) {
      m[0] = M0.x; m[1] = M0.y; m[2] = M0.z; m[3] = M0.w;
      m[4] = M1.x; m[5] = M1.y; m[6] = M1.z; m[7] = M1.w;
    }
  }

  float res[8];
#pragma unroll
  for (int j = 0; j < 8; ++j) {
    float mx = fmaxf(fmaxf(cmax[j], cmax[j + 1]), cmax[j + 2]);
    res[j] = ((mx - m[j]) > 0.5f) ? 1.0f : 0.0f;
  }
  float4* bo = (float4*)(border + b * HWC + r * WW + c8);
  bo[0] = make_float4(res[0], res[1], res[2], res[3]);
  bo[1] = make_float4(res[4], res[5], res[6], res[7]);
}

// ---------------------------------------------------------------------------
// Kernel B: vertical EDT stage (min distance in rows to border, capped at
// BIG), writes g^2. Segmented scan: block = 64 columns x 4 segments of 64
// rows; local scans with carry composition across segments.
__global__ __launch_bounds__(256) void vdist_kernel(
    const float* __restrict__ border, float* __restrict__ g2) {
  __shared__ float tile[HH][64];  // local down-scan values (64 KB)
  __shared__ float sUp[4][64];    // local up-scan value at segment start
  int wl = threadIdx.x & 63;
  int seg = threadIdx.x >> 6;
  int b = blockIdx.x >> 2;             // WW/64 = 4 column tiles per image
  int wbase = (blockIdx.x & 3) * 64;
  int w = wbase + wl;
  int rs = seg * 64;
  const float* bp = border + b * HWC + w;

  // Phase A: local down-scan (init 2048 ~ "no border yet"), collect border
  // bits for this segment in a register mask.
  unsigned long long bits = 0ULL;
  float carry = 2048.0f;
  for (int i = 0; i < 64; ++i) {
    float bv = bp[(rs + i) * WW];
    bool isb = bv > 0.5f;
    bits |= (unsigned long long)isb << i;
    carry = isb ? 0.0f : carry + 1.0f;
    tile[rs + i][wl] = carry;
  }
  // Local up value at segment start = index of lowest set bit (or large).
  sUp[seg][wl] = bits ? (float)(__ffsll(bits) - 1) : 2112.0f;
  __syncthreads();

  // Carry-in composition across segments (<=3 steps each).
  float cinD = BIGF;
  for (int s = 0; s < seg; ++s) {
    float e = tile[s * 64 + 63][wl];           // local down at segment end
    cinD = (e < 64.0f) ? e : cinD + 64.0f;
  }
  float cinU = BIGF;
  for (int s = 3; s > seg; --s) {
    float e = sUp[s][wl];
    cinU = (e < 64.0f) ? e : cinU + 64.0f;
  }

  // Phase B: corrected down = min(local, cinD + i + 1); corrected up via
  // register rescan of bits; g = min(down, up, BIG); store g^2.
  float* gp = g2 + b * HWC + w;
  float carry2 = 2048.0f;
  for (int i = 63; i >= 0; --i) {
    bool isb = (bits >> i) & 1ULL;
    carry2 = isb ? 0.0f : carry2 + 1.0f;
    float d = fminf(tile[rs + i][wl], cinD + (float)(i + 1));
    float u = fminf(carry2, cinU + (float)(64 - i));
    float g = fminf(fminf(d, u), BIGF);
    gp[(rs + i) * WW] = g * g;
  }
}

// ---------------------------------------------------------------------------
// Kernel C: per-row min-plus over columns (exact EDT stage 2) fused with
// weight + L1 + mean reduction. One block (256 threads) per (b,r) row.
// Waves whose 64 lanes are all mask==0 contribute exactly 0 -> skip all work.
__global__ __launch_bounds__(256) void row_loss_kernel(
    const float* __restrict__ g2, const float* __restrict__ mask,
    const float* __restrict__ rec, const float* __restrict__ im,
    float* __restrict__ out) {
  __shared__ float srow[WW];
  __shared__ float swave[4];
  int br = blockIdx.x;  // b*H + r
  int b = br / HH;
  int r = br % HH;
  int c = threadIdx.x;
  int base = b * HWC + r * WW;

  srow[c] = g2[base + c];
  float m = mask[base + c];
  __syncthreads();

  float local = 0.0f;
  if (__ballot(m > 0.5f) != 0ULL) {
    float cf = (float)c;
    float a0 = 4.0f * BIG2F, a1 = a0, a2 = a0, a3 = a0;
#pragma unroll 8
    for (int cp = 0; cp < WW; cp += 4) {
      float4 s4 = *(const float4*)(&srow[cp]);
      float d0 = cf - (float)cp;
      float d1 = d0 - 1.0f;
      float dd = d0 - 2.0f;
      float d3 = d0 - 3.0f;
      a0 = fminf(a0, fmaf(d0, d0, s4.x));
      a1 = fminf(a1, fmaf(d1, d1, s4.y));
      a2 = fminf(a2, fmaf(dd, dd, s4.z));
      a3 = fminf(a3, fmaf(d3, d3, s4.w));
    }
    float d2 = fminf(fminf(a0, a1), fminf(a2, a3));
    float dist = (d2 >= BIG2F) ? 0.0f : sqrtf(d2);
    float wgt = exp2f(dist * m * LOG2G) * m;  // gamma^(dist*mask) * mask

    int pbase = b * CC * HWC + r * WW + c;
    float acc = 0.0f;
#pragma unroll
    for (int ch = 0; ch < CC; ++ch)
      acc += fabsf(rec[pbase + ch * HWC] - im[pbase + ch * HWC]);
    local = wgt * acc;
  }

  // wave (64-lane) reduction, then block reduction, one atomic per block.
#pragma unroll
  for (int off = 32; off > 0; off >>= 1) local += __shfl_down(local, off, 64);
  int lane = c & 63, wid = c >> 6;
  if (lane == 0) swave[wid] = local;
  __syncthreads();
  if (c == 0) {
    float s = swave[0] + swave[1] + swave[2] + swave[3];
    atomicAdd(out, s * INV_N);
  }
}

// ---------------------------------------------------------------------------
extern "C" void kernel_launch(void* const* d_in, const int* in_sizes, int n_in,
                              void* d_out, int out_size, void* d_ws,
                              size_t ws_size, hipStream_t stream) {
  const float* rec = (const float*)d_in[0];
  const float* im = (const float*)d_in[1];
  const float* mask = (const float*)d_in[2];
  float* out = (float*)d_out;

  float* border = (float*)d_ws;                 // B*H*W floats = 2 MB
  float* g2 = (float*)d_ws + (size_t)BB * HWC;  // B*H*W floats = 2 MB

  border_kernel<<<BB * HH * (WW / 8) / 256, 256, 0, stream>>>(mask, border, out);
  vdist_kernel<<<BB * (WW / 64), 256, 0, stream>>>(border, g2);
  row_loss_kernel<<<BB * HH, 256, 0, stream>>>(g2, mask, rec, im, out);
}

// Round 4
// 37.735 us; speedup vs baseline: 2.1189x; 1.1677x over previous
//
#include <hip/hip_runtime.h>

// Problem constants: B=8, C=3, H=W=256, mask (B,1,H,W)
#define BB 8
#define CC 3
#define HH 256
#define WW 256
#define HWC (HH * WW)

// BIG = H+W = 512 ; BIG^2 = 262144. With any border present, every pixel's
// D^2 <= 2*255^2 < BIG^2, so (d2 >= BIG^2) <=> image has no border pixels
// (reference leaves D = 0 in that case).
#define BIGF 512.0f
#define BIG2F 262144.0f

#define LOG2G (-0.014499569695115089f)  // log2(0.99)
#define INV_N (1.0f / 1572864.0f)       // 1/(B*C*H*W)

#define CT 16   // columns per tile
#define SEGS 16 // row segments per column
#define SR 16   // rows per segment

// ---------------------------------------------------------------------------
// Kernel 1: fused border (3x3 maxpool - mask) + vertical EDT stage, writes
// g^2 = (min row-distance to border, capped at BIG)^2. Also zeroes d_out.
// Block = (b, 16-col tile): 256 threads = 16 cols x 16 segments x 16 rows.
__global__ __launch_bounds__(256) void bv_kernel(
    const float* __restrict__ mask, float* __restrict__ g2,
    float* __restrict__ out) {
  __shared__ float svmax[HH][CT + 3];      // vertical max3, cols c0-1..c0+16 (idx 0..17), stride 19
  __shared__ float sDownEnd[SEGS][CT];     // local down-scan value at segment end
  __shared__ float sUpFirst[SEGS][CT];     // first border index within segment

  if (blockIdx.x == 0 && threadIdx.x == 0) out[0] = 0.0f;

  int cl = threadIdx.x & (CT - 1);
  int seg = threadIdx.x / CT;
  int tile = blockIdx.x & (WW / CT - 1);  // 16 tiles per image
  int b = blockIdx.x / (WW / CT);
  int c0 = tile * CT;
  int c = c0 + cl;
  int rs = seg * SR;
  const float* mb = mask + b * HWC;

  // Own-column mask values for rows rs-1..rs+16 (row-clamped; duplicates at
  // image edges are harmless under max -- matches 'SAME' pooling).
  float mcol[SR + 2];
#pragma unroll
  for (int i = 0; i < SR + 2; ++i) {
    int r = rs - 1 + i;
    r = r < 0 ? 0 : (r > HH - 1 ? HH - 1 : r);
    mcol[i] = mb[r * WW + c];
  }
#pragma unroll
  for (int i = 0; i < SR; ++i)
    svmax[rs + i][cl + 1] = fmaxf(fmaxf(mcol[i], mcol[i + 1]), mcol[i + 2]);

  // Halo columns (c0-1, c0+16), column-clamped.
  if (cl == 0 || cl == CT - 1) {
    int ch = (cl == 0) ? (c0 - 1 < 0 ? 0 : c0 - 1)
                       : (c0 + CT > WW - 1 ? WW - 1 : c0 + CT);
    int si = (cl == 0) ? 0 : CT + 1;
    int r0 = rs - 1 < 0 ? 0 : rs - 1;
    float h0 = mb[r0 * WW + ch];
    float h1 = mb[rs * WW + ch];
#pragma unroll
    for (int i = 0; i < SR; ++i) {
      int r2 = rs + 1 + i;
      r2 = r2 > HH - 1 ? HH - 1 : r2;
      float h2 = mb[r2 * WW + ch];
      svmax[rs + i][si] = fmaxf(fmaxf(h0, h1), h2);
      h0 = h1;
      h1 = h2;
    }
  }
  __syncthreads();

  // Border bits for this (column, segment): 3x3 max - mask > 0.5.
  unsigned int bits = 0;
#pragma unroll
  for (int i = 0; i < SR; ++i) {
    float mx = fmaxf(fmaxf(svmax[rs + i][cl], svmax[rs + i][cl + 1]),
                     svmax[rs + i][cl + 2]);
    if ((mx - mcol[i + 1]) > 0.5f) bits |= (1u << i);
  }

  // Segment summaries.
  float carry = 4096.0f;
#pragma unroll
  for (int i = 0; i < SR; ++i) carry = (bits >> i & 1u) ? 0.0f : carry + 1.0f;
  sDownEnd[seg][cl] = carry;  // < SR iff segment contains a border
  sUpFirst[seg][cl] = bits ? (float)(__ffs(bits) - 1) : 4096.0f;
  __syncthreads();

  // Carry composition across segments (image-boundary init = BIG).
  float cinD = BIGF;
  for (int s = 0; s < seg; ++s) {
    float e = sDownEnd[s][cl];
    cinD = (e < (float)SR) ? e : cinD + (float)SR;
  }
  float cinU = BIGF;
  for (int s = SEGS - 1; s > seg; --s) {
    float f = sUpFirst[s][cl];
    cinU = (f < (float)SR) ? f : cinU + (float)SR;
  }

  // Final corrected scans from register bits; write g^2.
  float up[SR];
  float cu = 4096.0f;
#pragma unroll
  for (int i = SR - 1; i >= 0; --i) {
    cu = (bits >> i & 1u) ? 0.0f : cu + 1.0f;
    up[i] = cu;
  }
  float* gp = g2 + b * HWC + c;
  float cd = 4096.0f;
#pragma unroll
  for (int i = 0; i < SR; ++i) {
    cd = (bits >> i & 1u) ? 0.0f : cd + 1.0f;
    float d = fminf(cd, cinD + (float)(i + 1));
    float u = fminf(up[i], cinU + (float)(SR - i));
    float g = fminf(fminf(d, u), BIGF);
    gp[(rs + i) * WW] = g * g;
  }
}

// ---------------------------------------------------------------------------
// Kernel 2: per-row min-plus over columns (exact EDT stage 2) fused with
// weight + L1 + mean reduction. One block (256 threads) per (b,r) row.
// Waves whose 64 lanes are all mask==0 contribute exactly 0 -> skip work.
__global__ __launch_bounds__(256) void row_loss_kernel(
    const float* __restrict__ g2, const float* __restrict__ mask,
    const float* __restrict__ rec, const float* __restrict__ im,
    float* __restrict__ out) {
  __shared__ float srow[WW];
  __shared__ float swave[4];
  int br = blockIdx.x;  // b*H + r
  int b = br / HH;
  int r = br % HH;
  int c = threadIdx.x;
  int base = b * HWC + r * WW;

  srow[c] = g2[base + c];
  float m = mask[base + c];
  __syncthreads();

  float local = 0.0f;
  if (__ballot(m > 0.5f) != 0ULL) {
    float cf = (float)c;
    float a0 = 4.0f * BIG2F, a1 = a0, a2 = a0, a3 = a0;
#pragma unroll 8
    for (int cp = 0; cp < WW; cp += 4) {
      float4 s4 = *(const float4*)(&srow[cp]);
      float d0 = cf - (float)cp;
      float d1 = d0 - 1.0f;
      float dd = d0 - 2.0f;
      float d3 = d0 - 3.0f;
      a0 = fminf(a0, fmaf(d0, d0, s4.x));
      a1 = fminf(a1, fmaf(d1, d1, s4.y));
      a2 = fminf(a2, fmaf(dd, dd, s4.z));
      a3 = fminf(a3, fmaf(d3, d3, s4.w));
    }
    float d2 = fminf(fminf(a0, a1), fminf(a2, a3));
    float dist = (d2 >= BIG2F) ? 0.0f : sqrtf(d2);
    float wgt = exp2f(dist * m * LOG2G) * m;  // gamma^(dist*mask) * mask

    int pbase = b * CC * HWC + r * WW + c;
    float acc = 0.0f;
#pragma unroll
    for (int ch = 0; ch < CC; ++ch)
      acc += fabsf(rec[pbase + ch * HWC] - im[pbase + ch * HWC]);
    local = wgt * acc;
  }

  // wave reduction, then block reduction, one atomic per block.
#pragma unroll
  for (int off = 32; off > 0; off >>= 1) local += __shfl_down(local, off, 64);
  int lane = c & 63, wid = c >> 6;
  if (lane == 0) swave[wid] = local;
  __syncthreads();
  if (c == 0) {
    float s = swave[0] + swave[1] + swave[2] + swave[3];
    atomicAdd(out, s * INV_N);
  }
}

// ---------------------------------------------------------------------------
extern "C" void kernel_launch(void* const* d_in, const int* in_sizes, int n_in,
                              void* d_out, int out_size, void* d_ws,
                              size_t ws_size, hipStream_t stream) {
  const float* rec = (const float*)d_in[0];
  const float* im = (const float*)d_in[1];
  const float* mask = (const float*)d_in[2];
  float* out = (float*)d_out;

  float* g2 = (float*)d_ws;  // B*H*W floats = 2 MB

  bv_kernel<<<BB * (WW / CT), 256, 0, stream>>>(mask, g2, out);
  row_loss_kernel<<<BB * HH, 256, 0, stream>>>(g2, mask, rec, im, out);
}

// Round 5
// 17.140 us; speedup vs baseline: 4.6648x; 2.2016x over previous
//
#include <hip/hip_runtime.h>

// Problem constants: B=8, C=3, H=W=256, mask (B,1,H,W)
#define BB 8
#define CC 3
#define HH 256
#define WW 256
#define HWC (HH * WW)

// BIG = H+W = 512 ; BIG^2 = 262144. With any border present, every pixel's
// D^2 <= 2*255^2 < BIG^2, so (d2 >= BIG^2) <=> image has no border pixels
// (reference leaves D = 0 in that case).
#define BIGF 512.0f
#define BIG2F 262144.0f

#define LOG2G (-0.014499569695115089f)  // log2(0.99)
#define INV_N (1.0f / 1572864.0f)       // 1/(B*C*H*W)

#define CT 16   // columns per tile
#define SEGS 16 // row segments per column
#define SR 16   // rows per segment

#define NROWBLK (BB * HH)  // row_loss grid size (2048)

// ---------------------------------------------------------------------------
// Kernel 1: fused border (3x3 maxpool - mask) + vertical EDT stage, writes
// g^2 = (min row-distance to border, capped at BIG)^2.
// Block = (b, 16-col tile): 256 threads = 16 cols x 16 segments x 16 rows.
__global__ __launch_bounds__(256) void bv_kernel(
    const float* __restrict__ mask, float* __restrict__ g2) {
  __shared__ float svmax[HH][CT + 3];      // vertical max3, cols c0-1..c0+16, stride 19
  __shared__ float sDownEnd[SEGS][CT];     // local down-scan value at segment end
  __shared__ float sUpFirst[SEGS][CT];     // first border index within segment

  int cl = threadIdx.x & (CT - 1);
  int seg = threadIdx.x / CT;
  int tile = blockIdx.x & (WW / CT - 1);  // 16 tiles per image
  int b = blockIdx.x / (WW / CT);
  int c0 = tile * CT;
  int c = c0 + cl;
  int rs = seg * SR;
  const float* mb = mask + b * HWC;

  // Own-column mask values for rows rs-1..rs+16 (row-clamped; duplicates at
  // image edges are harmless under max -- matches 'SAME' pooling).
  float mcol[SR + 2];
#pragma unroll
  for (int i = 0; i < SR + 2; ++i) {
    int r = rs - 1 + i;
    r = r < 0 ? 0 : (r > HH - 1 ? HH - 1 : r);
    mcol[i] = mb[r * WW + c];
  }
#pragma unroll
  for (int i = 0; i < SR; ++i)
    svmax[rs + i][cl + 1] = fmaxf(fmaxf(mcol[i], mcol[i + 1]), mcol[i + 2]);

  // Halo columns (c0-1, c0+16), column-clamped.
  if (cl == 0 || cl == CT - 1) {
    int ch = (cl == 0) ? (c0 - 1 < 0 ? 0 : c0 - 1)
                       : (c0 + CT > WW - 1 ? WW - 1 : c0 + CT);
    int si = (cl == 0) ? 0 : CT + 1;
    int r0 = rs - 1 < 0 ? 0 : rs - 1;
    float h0 = mb[r0 * WW + ch];
    float h1 = mb[rs * WW + ch];
#pragma unroll
    for (int i = 0; i < SR; ++i) {
      int r2 = rs + 1 + i;
      r2 = r2 > HH - 1 ? HH - 1 : r2;
      float h2 = mb[r2 * WW + ch];
      svmax[rs + i][si] = fmaxf(fmaxf(h0, h1), h2);
      h0 = h1;
      h1 = h2;
    }
  }
  __syncthreads();

  // Border bits for this (column, segment): 3x3 max - mask > 0.5.
  unsigned int bits = 0;
#pragma unroll
  for (int i = 0; i < SR; ++i) {
    float mx = fmaxf(fmaxf(svmax[rs + i][cl], svmax[rs + i][cl + 1]),
                     svmax[rs + i][cl + 2]);
    if ((mx - mcol[i + 1]) > 0.5f) bits |= (1u << i);
  }

  // Segment summaries.
  float carry = 4096.0f;
#pragma unroll
  for (int i = 0; i < SR; ++i) carry = (bits >> i & 1u) ? 0.0f : carry + 1.0f;
  sDownEnd[seg][cl] = carry;  // < SR iff segment contains a border
  sUpFirst[seg][cl] = bits ? (float)(__ffs(bits) - 1) : 4096.0f;
  __syncthreads();

  // Carry composition across segments (image-boundary init = BIG).
  float cinD = BIGF;
  for (int s = 0; s < seg; ++s) {
    float e = sDownEnd[s][cl];
    cinD = (e < (float)SR) ? e : cinD + (float)SR;
  }
  float cinU = BIGF;
  for (int s = SEGS - 1; s > seg; --s) {
    float f = sUpFirst[s][cl];
    cinU = (f < (float)SR) ? f : cinU + (float)SR;
  }

  // Final corrected scans from register bits; write g^2.
  float up[SR];
  float cu = 4096.0f;
#pragma unroll
  for (int i = SR - 1; i >= 0; --i) {
    cu = (bits >> i & 1u) ? 0.0f : cu + 1.0f;
    up[i] = cu;
  }
  float* gp = g2 + b * HWC + c;
  float cd = 4096.0f;
#pragma unroll
  for (int i = 0; i < SR; ++i) {
    cd = (bits >> i & 1u) ? 0.0f : cd + 1.0f;
    float d = fminf(cd, cinD + (float)(i + 1));
    float u = fminf(up[i], cinU + (float)(SR - i));
    float g = fminf(fminf(d, u), BIGF);
    gp[(rs + i) * WW] = g * g;
  }
}

// ---------------------------------------------------------------------------
// Kernel 2: per-row min-plus over columns (exact EDT stage 2) fused with
// weight + L1; writes one partial sum per block (NO global atomic -- the
// 2048 same-address atomics serialize device-wide). One block per (b,r) row.
__global__ __launch_bounds__(256) void row_loss_kernel(
    const float* __restrict__ g2, const float* __restrict__ mask,
    const float* __restrict__ rec, const float* __restrict__ im,
    float* __restrict__ partials) {
  __shared__ float srow[WW];
  __shared__ float swave[4];
  int br = blockIdx.x;  // b*H + r
  int b = br / HH;
  int r = br % HH;
  int c = threadIdx.x;
  int base = b * HWC + r * WW;

  srow[c] = g2[base + c];
  float m = mask[base + c];
  __syncthreads();

  float local = 0.0f;
  if (__ballot(m > 0.5f) != 0ULL) {  // waves with all mask==0 contribute 0
    float cf = (float)c;
    float a0 = 4.0f * BIG2F, a1 = a0, a2 = a0, a3 = a0;
#pragma unroll 8
    for (int cp = 0; cp < WW; cp += 4) {
      float4 s4 = *(const float4*)(&srow[cp]);
      float d0 = cf - (float)cp;
      float d1 = d0 - 1.0f;
      float dd = d0 - 2.0f;
      float d3 = d0 - 3.0f;
      a0 = fminf(a0, fmaf(d0, d0, s4.x));
      a1 = fminf(a1, fmaf(d1, d1, s4.y));
      a2 = fminf(a2, fmaf(dd, dd, s4.z));
      a3 = fminf(a3, fmaf(d3, d3, s4.w));
    }
    float d2 = fminf(fminf(a0, a1), fminf(a2, a3));
    float dist = (d2 >= BIG2F) ? 0.0f : sqrtf(d2);
    float wgt = exp2f(dist * m * LOG2G) * m;  // gamma^(dist*mask) * mask

    int pbase = b * CC * HWC + r * WW + c;
    float acc = 0.0f;
#pragma unroll
    for (int ch = 0; ch < CC; ++ch)
      acc += fabsf(rec[pbase + ch * HWC] - im[pbase + ch * HWC]);
    local = wgt * acc;
  }

  // wave reduction, then block reduction, one partial store per block.
#pragma unroll
  for (int off = 32; off > 0; off >>= 1) local += __shfl_down(local, off, 64);
  int lane = c & 63, wid = c >> 6;
  if (lane == 0) swave[wid] = local;
  __syncthreads();
  if (c == 0)
    partials[br] = swave[0] + swave[1] + swave[2] + swave[3];
}

// ---------------------------------------------------------------------------
// Kernel 3: finalize -- one block sums the 2048 partials, writes the mean.
__global__ __launch_bounds__(256) void finalize_kernel(
    const float* __restrict__ partials, float* __restrict__ out) {
  __shared__ float swave[4];
  int t = threadIdx.x;
  float4 p0 = *(const float4*)(partials + t * 8);
  float4 p1 = *(const float4*)(partials + t * 8 + 4);
  float local = (p0.x + p0.y) + (p0.z + p0.w) + (p1.x + p1.y) + (p1.z + p1.w);
#pragma unroll
  for (int off = 32; off > 0; off >>= 1) local += __shfl_down(local, off, 64);
  int lane = t & 63, wid = t >> 6;
  if (lane == 0) swave[wid] = local;
  __syncthreads();
  if (t == 0)
    out[0] = (swave[0] + swave[1] + swave[2] + swave[3]) * INV_N;
}

// ---------------------------------------------------------------------------
extern "C" void kernel_launch(void* const* d_in, const int* in_sizes, int n_in,
                              void* d_out, int out_size, void* d_ws,
                              size_t ws_size, hipStream_t stream) {
  const float* rec = (const float*)d_in[0];
  const float* im = (const float*)d_in[1];
  const float* mask = (const float*)d_in[2];
  float* out = (float*)d_out;

  float* g2 = (float*)d_ws;                        // B*H*W floats = 2 MB
  float* partials = (float*)d_ws + (size_t)BB * HWC;  // 2048 floats

  bv_kernel<<<BB * (WW / CT), 256, 0, stream>>>(mask, g2);
  row_loss_kernel<<<NROWBLK, 256, 0, stream>>>(g2, mask, rec, im, partials);
  finalize_kernel<<<1, 256, 0, stream>>>(partials, out);
}